// Round 1
// baseline (19.514 us; speedup 1.0000x reference)
//
#include <hip/hip_runtime.h>

// Product_50242527428657: out[b,o] = prod_i (x[b,i]*w[o,i] + 1) - (1-ALPHA)*sum_i(x*w) - 1 + bias[o]
// ALPHA == 1.0 exactly -> the this_sum term's coefficient is 0.0 (0*finite == 0 in the
// reference as well), so only the product path is computed.
//
// B=1024, IN=256, OUT=512, fp32. VALU-bound (no product-MFMA exists; no fp32 MFMA on CDNA4).
// Tiling: block = 16 batch rows x 64 out cols, 256 threads, grid (8,64)=512 blocks
//   -> 2 blocks/CU (LDS 80KB), 8 waves/CU for latency hiding, all 256 CUs busy.
// LDS: full-K tiles, float4-chunk XOR swizzle so staging writes AND compute reads are
//   bank-conflict-free (different-row same-column reads are the classic 32-way pattern).

#define BATCH 1024
#define IN    256
#define OUT   512

#define BM 16            // batch rows per block
#define BN 64            // out cols per block
#define NK4 (IN / 4)     // 64 float4 chunks along K

__global__ __launch_bounds__(256) void product_kernel(
    const float* __restrict__ x, const float* __restrict__ w,
    const float* __restrict__ bias, float* __restrict__ out)
{
    // chunk-swizzled LDS tiles (float4 granularity keeps 16B alignment for b128 ops)
    __shared__ float4 xs[BM * NK4];   // 16 KB; phys chunk = c4 ^ (row & 7)
    __shared__ float4 ws[BN * NK4];   // 64 KB; phys chunk = c4 ^ ((row >> 2) & 7)

    const int tid = threadIdx.x;
    const int o0  = blockIdx.x * BN;
    const int b0  = blockIdx.y * BM;

    const float4* x4 = (const float4*)x;   // [BATCH][NK4]
    const float4* w4 = (const float4*)w;   // [OUT][NK4]

    // ---- stage x tile: BM*NK4 = 1024 chunks, coalesced 1KB/wave global reads ----
    #pragma unroll
    for (int i = tid; i < BM * NK4; i += 256) {
        const int row = i >> 6, c4 = i & 63;
        xs[row * NK4 + (c4 ^ (row & 7))] = x4[(b0 + row) * NK4 + c4];
    }
    // ---- stage w tile: BN*NK4 = 4096 chunks ----
    #pragma unroll
    for (int i = tid; i < BN * NK4; i += 256) {
        const int row = i >> 6, c4 = i & 63;
        ws[row * NK4 + (c4 ^ ((row >> 2) & 7))] = w4[(o0 + row) * NK4 + c4];
    }
    __syncthreads();

    const int tx  = tid & 15;   // out-col group: cols o0 + 4*tx .. +3
    const int ty  = tid >> 4;   // batch row: b0 + ty
    const int sxa = ty & 7;     // xs row-swizzle for row=ty
    const int sxb = tx & 7;     // ws row-swizzle for rows 4*tx..+3 (row>>2 == tx)

    const float4* xrow = &xs[ty * NK4];
    const float4* wr0  = &ws[(tx * 4 + 0) * NK4];
    const float4* wr1  = &ws[(tx * 4 + 1) * NK4];
    const float4* wr2  = &ws[(tx * 4 + 2) * NK4];
    const float4* wr3  = &ws[(tx * 4 + 3) * NK4];

    float p0 = 1.0f, p1 = 1.0f, p2 = 1.0f, p3 = 1.0f;

    #pragma unroll 8
    for (int k4 = 0; k4 < NK4; ++k4) {
        const float4 a  = xrow[k4 ^ sxa];
        const float4 q0 = wr0[k4 ^ sxb];
        const float4 q1 = wr1[k4 ^ sxb];
        const float4 q2 = wr2[k4 ^ sxb];
        const float4 q3 = wr3[k4 ^ sxb];
        // sequential in k (matches reference reduction order): fma then mul
        p0 *= __builtin_fmaf(a.x, q0.x, 1.0f);
        p1 *= __builtin_fmaf(a.x, q1.x, 1.0f);
        p2 *= __builtin_fmaf(a.x, q2.x, 1.0f);
        p3 *= __builtin_fmaf(a.x, q3.x, 1.0f);
        p0 *= __builtin_fmaf(a.y, q0.y, 1.0f);
        p1 *= __builtin_fmaf(a.y, q1.y, 1.0f);
        p2 *= __builtin_fmaf(a.y, q2.y, 1.0f);
        p3 *= __builtin_fmaf(a.y, q3.y, 1.0f);
        p0 *= __builtin_fmaf(a.z, q0.z, 1.0f);
        p1 *= __builtin_fmaf(a.z, q1.z, 1.0f);
        p2 *= __builtin_fmaf(a.z, q2.z, 1.0f);
        p3 *= __builtin_fmaf(a.z, q3.z, 1.0f);
        p0 *= __builtin_fmaf(a.w, q0.w, 1.0f);
        p1 *= __builtin_fmaf(a.w, q1.w, 1.0f);
        p2 *= __builtin_fmaf(a.w, q2.w, 1.0f);
        p3 *= __builtin_fmaf(a.w, q3.w, 1.0f);
    }

    // ---- epilogue: out = prod - 1 + bias, float4 coalesced store ----
    const float4 bv = ((const float4*)bias)[(o0 >> 2) + tx];
    float4 o;
    o.x = p0 - 1.0f + bv.x;
    o.y = p1 - 1.0f + bv.y;
    o.z = p2 - 1.0f + bv.z;
    o.w = p3 - 1.0f + bv.w;
    ((float4*)out)[(size_t)(b0 + ty) * (OUT / 4) + (o0 >> 2) + tx] = o;
}

extern "C" void kernel_launch(void* const* d_in, const int* in_sizes, int n_in,
                              void* d_out, int out_size, void* d_ws, size_t ws_size,
                              hipStream_t stream) {
    const float* x    = (const float*)d_in[0];   // (1024, 256)
    const float* wgt  = (const float*)d_in[1];   // (512, 256)
    const float* bias = (const float*)d_in[2];   // (512,)
    float* out        = (float*)d_out;           // (1024, 512)

    dim3 grid(OUT / BN, BATCH / BM);   // (8, 64) = 512 blocks
    dim3 block(256);
    product_kernel<<<grid, block, 0, stream>>>(x, wgt, bias, out);
}

// Round 2
// 19.379 us; speedup vs baseline: 1.0070x; 1.0070x over previous
//
#include <hip/hip_runtime.h>

// Product_50242527428657: out[b,o] = prod_k (x[b,k]*w[o,k] + 1) - 1 + bias[o]   (ALPHA==1)
// B=1024, IN=256, OUT=512, fp32. No fp32 MFMA -> pure VALU kernel; floor = 3.4us.
//
// Round-2 design (fix: round-1 was LDS-instruction-bound at ~12.8us of LDS-pipe time):
//  - 512 blocks (32x16 spatial tiles of 32x32 outputs), 256 threads, 2 blocks/CU, 8 waves/CU.
//  - Per-thread 8x8 register tile (0.25 LDS floats/triple, was 1.25) with in-block 16-way
//    K-split: thread (sb,ty,tx) computes partial products over k in [sb*16,(sb+1)*16).
//  - LDS rows padded to 65 float4-chunks + row-interleaved ownership (rows ty+4i): all
//    main-loop ds_read_b128 are base + compile-time immediate offset, <=2-way conflicts.
//  - Combine: 2 shfl_xor multiply steps (sb within wave) + 16KB LDS exchange across waves.
//    Product reassociation is fine: threshold 0.266, round-1 absmax was 0.0078.

#define BATCH 1024
#define IN    256
#define OUT   512
#define NK4   (IN / 4)     // 64 float4 chunks along K
#define LDK   (NK4 + 1)    // 65: +1 chunk row pad -> bank spread with linear addressing

__global__ __launch_bounds__(256, 2) void product_kernel(
    const float* __restrict__ x, const float* __restrict__ w,
    const float* __restrict__ bias, float* __restrict__ out)
{
    __shared__ float4 xs4[32 * LDK];   // 33.28 KB, x tile rows b0..b0+31
    __shared__ float4 ws4[32 * LDK];   // 33.28 KB, w tile rows o0..o0+31

    const int tid  = threadIdx.x;
    const int tx   = tid & 3;          // w-row group: cols tx + 4j
    const int ty   = (tid >> 2) & 3;   // x-row group: rows ty + 4i
    const int sbl  = (tid >> 4) & 3;   // k-split index within wave (lane bits 4,5)
    const int wid  = tid >> 6;         // wave 0..3
    const int sb   = wid * 4 + sbl;    // k-split 0..15: k in [sb*16, sb*16+16)
    const int lane = tid & 63;

    const int o0 = blockIdx.x * 32;
    const int b0 = blockIdx.y * 32;

    const float4* x4g = (const float4*)x;   // [1024][64]
    const float4* w4g = (const float4*)w;   // [512][64]

    // ---- stage full-K tiles: each wave stages whole rows (64 contiguous chunks) ----
    #pragma unroll
    for (int it = 0; it < 16; ++it) {
        const int idx = it * 4 + wid;                       // 0..63, wave-uniform
        if (idx < 32) xs4[idx * LDK + lane]        = x4g[(b0 + idx) * NK4 + lane];
        else          ws4[(idx - 32) * LDK + lane] = w4g[(o0 + idx - 32) * NK4 + lane];
    }
    __syncthreads();

    // ---- main loop: 4 chunks (16 k) per thread, 64 accumulators ----
    float acc[8][8];
    #pragma unroll
    for (int i = 0; i < 8; ++i)
        #pragma unroll
        for (int j = 0; j < 8; ++j) acc[i][j] = 1.0f;

    const float4* xb = xs4 + ty * LDK + sb * 4;   // row ty, chunk sb*4; +i*4*LDK, +p imm
    const float4* wb = ws4 + tx * LDK + sb * 4;

    #pragma unroll
    for (int p = 0; p < 4; ++p) {
        float4 xv[8], wv[8];
        #pragma unroll
        for (int i = 0; i < 8; ++i) xv[i] = xb[i * 4 * LDK + p];
        #pragma unroll
        for (int j = 0; j < 8; ++j) wv[j] = wb[j * 4 * LDK + p];

        #define KSTEP(COMP)                                                  \
        {   _Pragma("unroll")                                                \
            for (int i = 0; i < 8; ++i) {                                    \
                const float xc = xv[i].COMP;                                 \
                _Pragma("unroll")                                            \
                for (int j = 0; j < 8; ++j)                                  \
                    acc[i][j] *= __builtin_fmaf(xc, wv[j].COMP, 1.0f);       \
            }                                                                \
        }
        KSTEP(x) KSTEP(y) KSTEP(z) KSTEP(w)
        #undef KSTEP
    }

    // ---- combine 1: multiply partials across sbl (lane bits 4,5) in-wave ----
    #pragma unroll
    for (int i = 0; i < 8; ++i)
        #pragma unroll
        for (int j = 0; j < 8; ++j) {
            float v = acc[i][j];
            v *= __shfl_xor(v, 16, 64);
            v *= __shfl_xor(v, 32, 64);
            acc[i][j] = v;
        }

    // ---- combine 2: cross-wave via LDS (alias over xs4; barrier-protected) ----
    __syncthreads();                       // all xs/ws reads done before overwrite
    float* part = (float*)xs4;             // [4 waves][32 rows][32 cols] = 16 KB
    #pragma unroll
    for (int ii = 0; ii < 2; ++ii) {       // lane sbl stores i = 2*sbl + ii
        const int i = sbl * 2 + ii;
        #pragma unroll
        for (int j = 0; j < 8; ++j)
            part[wid * 1024 + (ty + 4 * i) * 32 + (tx + 4 * j)] = acc[i][j];
    }
    __syncthreads();

    // ---- epilogue: multiply 4 wave-partials (fixed order), -1 + bias, store ----
    const int row = tid >> 3;              // 0..31
    const int cg  = tid & 7;               // float4 col group
    const float4* part4 = (const float4*)part;
    const float4 q0 = part4[0 * 256 + row * 8 + cg];
    const float4 q1 = part4[1 * 256 + row * 8 + cg];
    const float4 q2 = part4[2 * 256 + row * 8 + cg];
    const float4 q3 = part4[3 * 256 + row * 8 + cg];
    const float4 bv = ((const float4*)bias)[(o0 >> 2) + cg];
    float4 o;
    o.x = ((q0.x * q1.x) * q2.x) * q3.x - 1.0f + bv.x;
    o.y = ((q0.y * q1.y) * q2.y) * q3.y - 1.0f + bv.y;
    o.z = ((q0.z * q1.z) * q2.z) * q3.z - 1.0f + bv.z;
    o.w = ((q0.w * q1.w) * q2.w) * q3.w - 1.0f + bv.w;
    ((float4*)out)[(size_t)(b0 + row) * (OUT / 4) + (o0 >> 2) + cg] = o;
}

extern "C" void kernel_launch(void* const* d_in, const int* in_sizes, int n_in,
                              void* d_out, int out_size, void* d_ws, size_t ws_size,
                              hipStream_t stream) {
    const float* x    = (const float*)d_in[0];   // (1024, 256)
    const float* wgt  = (const float*)d_in[1];   // (512, 256)
    const float* bias = (const float*)d_in[2];   // (512,)
    float* out        = (float*)d_out;           // (1024, 512)

    dim3 grid(OUT / 32, BATCH / 32);   // (16, 32) = 512 blocks
    dim3 block(256);
    product_kernel<<<grid, block, 0, stream>>>(x, wgt, bias, out);
}